// Round 1
// baseline (549.815 us; speedup 1.0000x reference)
//
#include <hip/hip_runtime.h>

#define NB 256   // batches
#define ND 256   // d
#define NN 1024  // n

typedef _Float16 f16_t;
typedef _Float16 f16x8 __attribute__((ext_vector_type(8)));
typedef float    f32x4 __attribute__((ext_vector_type(4)));
typedef float    f32x16 __attribute__((ext_vector_type(16)));

// ---------------------------------------------------------------------------
// Fully fused kernel: one 512-thread block per batch (1 block/CU).
//   phase 1: G = A A^T via 32x32x16 f16 MFMA (double-buffered LDS staging),
//            epilogue writes swizzled fp16 G [256][256] into LDS (128 KB).
//   phase 2: register-resident power iteration (2 components, 3 iters each),
//            G sourced from LDS; results (va, vb, v1, v2, params) left in LDS.
//   phase 3: y = X*r + (c1*u1) v1^T + (c2*u2) v2^T over 16 column tiles,
//            one-tile-ahead register prefetch; partial buffers alias dead G.
// LDS: 128 KB (sbuf ∪ G ∪ spr) + ~4.6 KB aux = ~133 KB -> 1 block/CU.
// ---------------------------------------------------------------------------
__global__ __launch_bounds__(512, 2) void k_fused(const float* __restrict__ x,
                                                  const float* __restrict__ wvec,
                                                  float* __restrict__ y)
{
    __shared__ __align__(16) unsigned char smem[131072];
    __shared__ float sv[ND], sv1v[ND], sva[ND], svb[ND];
    __shared__ float sred[8], spar[8], sg1[64], sg2[64];

    const int t = threadIdx.x;
    const int b = blockIdx.x;
    const float* xb = x + (size_t)b * ND * NN;

    const int w    = t >> 6;     // wave 0..7
    const int lane = t & 63;
    const int fr   = lane & 31;
    const int half = lane >> 5;

    // ======================= phase 1: G = A A^T =============================
    {
        f16_t* sb0 = (f16_t*)smem;          // [2][256*64] staging, chunk-swizzled
        const int c8    = t & 7;            // 8-float chunk within 64-col slice
        const int rbase = t >> 3;           // 0..63
        f32x4 pf[8];

        auto issue = [&](int kc) {
            const float* base = xb + (size_t)kc * 64 + c8 * 8;
            #pragma unroll
            for (int kk = 0; kk < 4; ++kk) {
                const float* p = base + (size_t)(rbase + 64 * kk) * NN;
                pf[2 * kk]     = *(const f32x4*)p;
                pf[2 * kk + 1] = *(const f32x4*)(p + 4);
            }
        };
        auto commit = [&](int buf) {
            #pragma unroll
            for (int kk = 0; kk < 4; ++kk) {
                const int row = rbase + 64 * kk;
                f16x8 hh;
                #pragma unroll
                for (int j = 0; j < 4; ++j) {
                    hh[j]     = (f16_t)pf[2 * kk][j];
                    hh[4 + j] = (f16_t)pf[2 * kk + 1][j];
                }
                *(f16x8*)&sb0[buf * 16384 + row * 64 + ((c8 ^ (row & 7)) << 3)] = hh;
            }
        };

        const int mbase = (w & 3) * 64;   // 4 row-slabs of 64
        const int nbase = (w >> 2) * 128; // 2 col-slabs of 128

        f32x16 acc[2][4] = {};

        issue(0);
        commit(0);

        for (int kc = 0; kc < 16; ++kc) {
            __syncthreads();
            if (kc < 15) issue(kc + 1);
            const f16_t* sb = sb0 + (kc & 1) * 16384;
            #pragma unroll
            for (int ks = 0; ks < 4; ++ks) {
                const int ch = ks * 2 + half;   // 16B chunk: k = ks*16 + half*8 + j
                f16x8 bf[4];
                #pragma unroll
                for (int nb = 0; nb < 4; ++nb) {
                    const int row = nbase + nb * 32 + fr;
                    bf[nb] = *(const f16x8*)&sb[row * 64 + ((ch ^ (row & 7)) << 3)];
                }
                #pragma unroll
                for (int mb = 0; mb < 2; ++mb) {
                    const int row = mbase + mb * 32 + fr;
                    const f16x8 af = *(const f16x8*)&sb[row * 64 + ((ch ^ (row & 7)) << 3)];
                    #pragma unroll
                    for (int nb = 0; nb < 4; ++nb)
                        acc[mb][nb] = __builtin_amdgcn_mfma_f32_32x32x16_f16(
                            af, bf[nb], acc[mb][nb], 0, 0, 0);
                }
            }
            if (kc < 15) commit((kc + 1) & 1);
        }

        __syncthreads();   // all MFMA staging reads done before G overwrites sbuf

        // epilogue: acc -> swizzled fp16 G in LDS.
        // C/D layout (32x32): col = lane&31, row = (reg&3) + 8*(reg>>2) + 4*(lane>>5)
        // G element [row][col] lives at f16 index row*256 + ((col>>3 ^ (row&7))<<3) + (col&7)
        f16_t* G = (f16_t*)smem;
        #pragma unroll
        for (int mb = 0; mb < 2; ++mb)
            #pragma unroll
            for (int nb = 0; nb < 4; ++nb) {
                const int gcol = nbase + nb * 32 + fr;
                const int ci = gcol >> 3, cj = gcol & 7;
                #pragma unroll
                for (int reg = 0; reg < 16; ++reg) {
                    const int grow = mbase + mb * 32 + (reg & 3) + 8 * (reg >> 2) + 4 * half;
                    G[grow * 256 + ((ci ^ (grow & 7)) << 3) + cj] = (f16_t)acc[mb][nb][reg];
                }
            }
    }
    __syncthreads();

    // ================= phase 2: power iteration from LDS G ==================
    // thread (r = t>>1, h = t&1) holds 128 fp16 of G row r (half h) in regs.
    const f16_t* G = (const f16_t*)smem;
    const int r = t >> 1;
    const int h = t & 1;

    f16x8 g8[16];
    #pragma unroll
    for (int i = 0; i < 16; ++i) {
        const int c = h * 16 + i;
        g8[i] = *(const f16x8*)&G[r * 256 + ((c ^ (r & 7)) << 3)];
    }

    // prefetch phase-3 tile 0 now; HBM latency hides under the power iteration
    const int c4 = t & 15;     // float4 column group within 64-col tile
    const int rg = t >> 4;     // row group 0..31
    const float* xb3 = x + (size_t)b * ND * NN + c4 * 4;
    f32x4 xr[8];
    #pragma unroll
    for (int k = 0; k < 8; ++k)
        xr[k] = *(const f32x4*)(xb3 + (size_t)(rg + 32 * k) * NN);

    auto reduce = [&](float val) -> float {
        #pragma unroll
        for (int off = 32; off > 0; off >>= 1) val += __shfl_xor(val, off, 64);
        __syncthreads();                 // protect sred from previous readers
        if ((t & 63) == 0) sred[t >> 6] = val;
        __syncthreads();
        float s = 0.f;
        #pragma unroll
        for (int i = 0; i < 8; ++i) s += sred[i];
        return s;
    };

    auto rowdot = [&](void) -> float {   // full (G v)[r], duplicated in lane pair
        float acc = 0.f;
        const float* svh = sv + h * 128;
        #pragma unroll
        for (int i = 0; i < 16; ++i) {
            const f32x4 va = *(const f32x4*)&svh[i * 8];
            const f32x4 vb = *(const f32x4*)&svh[i * 8 + 4];
            #pragma unroll
            for (int j = 0; j < 4; ++j) {
                acc += (float)g8[i][j]     * va[j];
                acc += (float)g8[i][4 + j] * vb[j];
            }
        }
        acc += __shfl_xor(acc, 1, 64);   // combine halves: lanes t, t^1 adjacent
        return acc;
    };

    // ---------------- component 1 ----------------
    if (h == 0) sv[r] = wvec[r];
    __syncthreads();

    float s1 = 0.f, n1 = 1.f;
    for (int it = 0; it < 3; ++it) {
        const float p  = rowdot();
        const float pp = reduce(0.5f * p * p);          // rows duplicated x2
        const float nrm = fmaxf(sqrtf(pp), 1e-12f);
        if (it == 2) {
            const float pv = reduce(0.5f * p * sv[r]);  // v2^T G v2
            n1 = sqrtf(pv);
            s1 = sqrtf(pp) / n1;
            if (h == 0) sva[r] = sv[r];                 // va = v2
            sv1v[r] = p / nrm;                          // v1 (dup write, same value)
        }
        if (h == 0) sv[r] = p / nrm;
        __syncthreads();
    }

    // ---------------- component 2 (deflated) ----------------
    if (h == 0) sv[r] = wvec[r];
    __syncthreads();

    float s2 = 0.f, n2 = 1.f, d1b = 0.f;
    const float s1sq = s1 * s1;
    for (int it = 0; it < 3; ++it) {
        const float d1 = reduce(0.5f * sv1v[r] * sv[r]);    // v1 . v
        const float p  = rowdot() - s1sq * d1 * sv1v[r];    // G' v
        const float pp = reduce(0.5f * p * p);
        const float nrm = fmaxf(sqrtf(pp), 1e-12f);
        if (it == 2) {
            const float pv = reduce(0.5f * p * sv[r]);      // v2'^T G' v2'
            n2  = sqrtf(pv);
            s2  = sqrtf(pp) / n2;
            d1b = d1;
            if (h == 0) svb[r] = sv[r];                     // vb = v2'
        }
        if (h == 0) sv[r] = p / nrm;                        // final: sv = v2
        __syncthreads();
    }

    if (t == 0) {
        const float rrr = 1.f / (sqrtf(s2) + 1e-5f);
        spar[0] = 1.f / n1;             // inv_n1
        spar[1] = 1.f / n2;             // inv_n2
        spar[2] = s1 * d1b / n2;        // k21
        spar[3] = rrr;
        spar[4] = sqrtf(s1) - s1 * rrr; // c1
        spar[5] = sqrtf(s2) - s2 * rrr; // c2
    }
    __syncthreads();

    // ======================= phase 3: output ================================
    // spr buffers alias the (now dead) G region.
    float* spr1 = (float*)smem;            // [32][64]
    float* spr2 = spr1 + 32 * 64;

    const float rr  = spar[3];
    const float ia1 = spar[0], ia2 = spar[1], k21 = spar[2];
    const float c1  = spar[4], c2  = spar[5];
    float* yb = y + (size_t)b * ND * NN + c4 * 4;

    for (int tile = 0; tile < 16; ++tile) {
        // column-dot partials for this tile's 64 columns
        f32x4 a1 = {0.f, 0.f, 0.f, 0.f}, a2 = {0.f, 0.f, 0.f, 0.f};
        #pragma unroll
        for (int k = 0; k < 8; ++k) {
            const int row = rg + 32 * k;
            a1 += xr[k] * sva[row];
            a2 += xr[k] * svb[row];
        }
        *(f32x4*)&spr1[rg * 64 + c4 * 4] = a1;
        *(f32x4*)&spr2[rg * 64 + c4 * 4] = a2;

        // prefetch next tile while reductions + stores run
        f32x4 xn[8];
        if (tile < 15) {
            const float* xnb = xb3 + (tile + 1) * 64;
            #pragma unroll
            for (int k = 0; k < 8; ++k)
                xn[k] = *(const f32x4*)(xnb + (size_t)(rg + 32 * k) * NN);
        }
        __syncthreads();

        if (t < 64) {
            float u1 = 0.f, u2 = 0.f;
            #pragma unroll
            for (int g2 = 0; g2 < 32; ++g2) {
                u1 += spr1[g2 * 64 + t];
                u2 += spr2[g2 * 64 + t];
            }
            const float uu1 = u1 * ia1;                 // a1 / n1
            const float uu2 = u2 * ia2 - k21 * uu1;     // a2/n2 - k21*u1
            sg1[t] = c1 * uu1;
            sg2[t] = c2 * uu2;
        }
        __syncthreads();

        const f32x4 g1v = *(const f32x4*)&sg1[c4 * 4];
        const f32x4 g2v = *(const f32x4*)&sg2[c4 * 4];
        float* yt = yb + tile * 64;
        #pragma unroll
        for (int k = 0; k < 8; ++k) {
            const int row = rg + 32 * k;
            const f32x4 o = xr[k] * rr + g1v * sv1v[row] + g2v * sv[row];
            *(f32x4*)(yt + (size_t)row * NN) = o;
        }
        if (tile < 15) {
            #pragma unroll
            for (int k = 0; k < 8; ++k) xr[k] = xn[k];
        }
    }
}

// ---------------------------------------------------------------------------
extern "C" void kernel_launch(void* const* d_in, const int* in_sizes, int n_in,
                              void* d_out, int out_size, void* d_ws, size_t ws_size,
                              hipStream_t stream)
{
    const float* x = (const float*)d_in[0];
    const float* w = (const float*)d_in[1];
    float* out = (float*)d_out;

    k_fused<<<dim3(NB), dim3(512), 0, stream>>>(x, w, out);
}